// Round 12
// baseline (156.168 us; speedup 1.0000x reference)
//
#include <hip/hip_runtime.h>
#include <hip/hip_bf16.h>

#define B_ 2
#define S_ 2048
#define E_ 1024
#define H_ 16
#define D_ 64
#define M_ (B_*S_)   // 4096 rows

typedef unsigned short u16;
typedef __attribute__((ext_vector_type(8))) short short8;   // 8 bf16 (4 VGPRs)
typedef __attribute__((ext_vector_type(4))) short short4v;  // 4 bf16 (8 B)
typedef __attribute__((ext_vector_type(4))) float f32x4;    // 4 fp32 acc

__device__ __forceinline__ float b2f(u16 u) {
    union { float f; unsigned int i; } x; x.i = ((unsigned int)u) << 16; return x.f;
}
__device__ __forceinline__ u16 f2b(float f) {
    union { float f; unsigned int i; } x; x.f = f;
    unsigned int r = x.i + 0x7fffu + ((x.i >> 16) & 1u);   // RNE
    return (u16)(r >> 16);
}

// raw v_exp_f32 (2^x); inputs tiny (|x|<~1), no OCML fixups needed
#if __has_builtin(__builtin_amdgcn_exp2f)
__device__ __forceinline__ float ex2(float x) { return __builtin_amdgcn_exp2f(x); }
#else
__device__ __forceinline__ float ex2(float x) {
    float r; asm("v_exp_f32 %0, %1" : "=v"(r) : "v"(x)); return r;
}
#endif

// ---------------- fp32 -> bf16 bulk cast (+ zero the l-accumulator) ----------------
__global__ __launch_bounds__(256)
void cvt_kernel(const float* __restrict__ X,
                const float* __restrict__ Wq, const float* __restrict__ Wk,
                const float* __restrict__ Wv, const float* __restrict__ Wo,
                u16* __restrict__ Xb, u16* __restrict__ Wqb, u16* __restrict__ Wkb,
                u16* __restrict__ Wvb, u16* __restrict__ Wob,
                float* __restrict__ lsum)
{
    int bid = blockIdx.x;
    if (bid >= 8192) {                       // zero lsum: 64 blocks x 1024 floats
        size_t i4 = (size_t)(bid - 8192) * 256 + threadIdx.x;
        ((float4*)lsum)[i4] = make_float4(0.f, 0.f, 0.f, 0.f);
        return;
    }
    const float* src; u16* dst; int blk;
    if (bid < 4096) { src = X; dst = Xb; blk = bid; }
    else {
        int w = (bid - 4096) >> 10;
        blk = (bid - 4096) & 1023;
        src = (w == 0) ? Wq : (w == 1) ? Wk : (w == 2) ? Wv : Wo;
        dst = (w == 0) ? Wqb : (w == 1) ? Wkb : (w == 2) ? Wvb : Wob;
    }
    size_t i4 = (size_t)blk * 256 + threadIdx.x;     // float4 index
    float4 v = ((const float4*)src)[i4];
    short4v o;
    o.x = (short)f2b(v.x); o.y = (short)f2b(v.y);
    o.z = (short)f2b(v.z); o.w = (short)f2b(v.w);
    *(short4v*)(dst + i4 * 4) = o;
}

// ---------------- GEMM staging, BK=64 ----------------
// LDS rows of 64 shorts (128 B = 8 x 16B slots). Slot swizzle c' = c ^ ((r>>1)&7)
// absorbed into the global source address: lane-linear DMA placement (chunk q at
// LDS offset q*16B) + swizzled source -> fragment ds_read_b128 sweeps all 8
// slots, 2 rows/slot = 2-way = free. BK=64 halves the barrier/vmcnt(0) drains.
#define BN 128
#define BK 64

template<int ROWS>   // stages ROWS x 64 shorts with 4 waves (DMA path)
__device__ __forceinline__ void stage64(const u16* __restrict__ gbase, u16* lds,
                                        int ldg, int wave, int lane)
{
    constexpr int ITERS = ROWS * 8 / 256;    // 16B-chunks per thread
    #pragma unroll
    for (int n = 0; n < ITERS; ++n) {
        int q = (wave * ITERS + n) * 64 + lane;
        int r = q >> 3, slot = q & 7;
        int c = slot ^ ((r >> 1) & 7);
        const u16* g = gbase + (size_t)r * ldg + c * 8;
        u16* l = lds + (size_t)(wave * ITERS + n) * 512;   // wave-uniform base
        __builtin_amdgcn_global_load_lds(
            (const __attribute__((address_space(1))) unsigned int*)g,
            (__attribute__((address_space(3))) unsigned int*)l, 16, 0, 0);
    }
}

template<int BMT>
__device__ __forceinline__ void gemm_bt_acc(
    const u16* __restrict__ A, const u16* __restrict__ Bm,
    int Kd, int bm, int bn, f32x4 (*acc)[4])
{
    constexpr int NI = BMT / 32;             // 16-row tiles per wave in m
    __shared__ u16 lA[BMT * BK];
    __shared__ u16 lB[BN * BK];
    const int tid  = threadIdx.x;
    const int wave = tid >> 6, lane = tid & 63;
    const int quad = lane >> 4, l16 = lane & 15;
    const int wm = (wave & 1) * (BMT / 2), wn = (wave >> 1) * 64;

    for (int k0 = 0; k0 < Kd; k0 += BK) {
        stage64<BMT>(A  + (size_t)bm * Kd + k0, lA, Kd, wave, lane);
        stage64<BN>(Bm + (size_t)bn * Kd + k0, lB, Kd, wave, lane);
        __syncthreads();
        #pragma unroll
        for (int s = 0; s < 2; ++s) {        // two K=32 sub-steps per staged tile
            short8 af[NI], bf[4];
            #pragma unroll
            for (int i = 0; i < NI; ++i) {
                int R = wm + i * 16 + l16;
                int sc = s * 4 + quad;
                af[i] = *(const short8*)&lA[R * 64 + ((sc ^ ((R >> 1) & 7)) * 8)];
            }
            #pragma unroll
            for (int j = 0; j < 4; ++j) {
                int R = wn + j * 16 + l16;
                int sc = s * 4 + quad;
                bf[j] = *(const short8*)&lB[R * 64 + ((sc ^ ((R >> 1) & 7)) * 8)];
            }
            #pragma unroll
            for (int i = 0; i < NI; ++i)
                #pragma unroll
                for (int j = 0; j < 4; ++j)
                    acc[i][j] = __builtin_amdgcn_mfma_f32_16x16x32_bf16(af[i], bf[j], acc[i][j], 0, 0, 0);
        }
        __syncthreads();
    }
}

__global__ __launch_bounds__(256, 3)
void qkv_kernel(const u16* __restrict__ X,
                const u16* __restrict__ Wq, const u16* __restrict__ Wk, const u16* __restrict__ Wv,
                u16* __restrict__ Q, u16* __restrict__ K, u16* __restrict__ V)
{
    const u16* W = (blockIdx.z == 0) ? Wq : (blockIdx.z == 1) ? Wk : Wv;
    u16* C = (blockIdx.z == 0) ? Q : (blockIdx.z == 1) ? K : V;
    const int bm = blockIdx.x * 128, bn = blockIdx.y * BN;
    f32x4 acc[4][4];
    #pragma unroll
    for (int i = 0; i < 4; ++i)
        #pragma unroll
        for (int j = 0; j < 4; ++j) acc[i][j] = (f32x4){0.f,0.f,0.f,0.f};
    gemm_bt_acc<128>(X, W, E_, bm, bn, acc);

    const int wave = threadIdx.x >> 6, lane = threadIdx.x & 63;
    const int quad = lane >> 4, l16 = lane & 15;
    const int wm = (wave & 1) * 64, wn = (wave >> 1) * 64;
    #pragma unroll
    for (int i = 0; i < 4; ++i)
        #pragma unroll
        for (int j = 0; j < 4; ++j) {
            int row0 = bm + wm + i * 16 + quad * 4;
            int col  = bn + wn + j * 16 + l16;
            #pragma unroll
            for (int r = 0; r < 4; ++r)
                C[(size_t)(row0 + r) * E_ + col] = f2b(acc[i][j][r]);
        }
}

// ---------------- Out = (diag-p scaled V) @ Wo^T + V, scale fused into A-staging ----------------
// A K-tiles span exactly one head (k0 multiple of 64 = D), so p = ed/lsum is
// per-(row, k-iter) uniform. A staged via explicit load->scale->ds_write_b128
// into the SAME linear-by-chunk LDS layout the DMA produces (lane-linear
// writes = conflict-free; fragment reads unchanged). B (Wo) stays DMA, issued
// first so it's in flight during A's VALU scaling. p table (16 heads x 64
// rows) built once in LDS: one divide per entry.
__global__ __launch_bounds__(256, 4)
void out_kernel(const u16* __restrict__ V, const u16* __restrict__ Wo,
                const float* __restrict__ lsum, const float* __restrict__ ed,
                float* __restrict__ Out)
{
    __shared__ u16 lA[64 * BK];              // 8 KB
    __shared__ u16 lB[BN * BK];              // 16 KB
    __shared__ float lp[H_ * 64];            // 4 KB
    const int bm = blockIdx.x * 64, bn = blockIdx.y * BN;
    const int tid  = threadIdx.x;
    const int wave = tid >> 6, lane = tid & 63;
    const int quad = lane >> 4, l16 = lane & 15;
    const int wm = (wave & 1) * 32, wn = (wave >> 1) * 64;
    const int bb = bm >> 11, sbase = bm & (S_ - 1);   // batch & seq base (uniform in block)

    // p table: lp[h*64 + r] = ed/lsum at (bb, h, sbase+r)
    #pragma unroll
    for (int n = 0; n < 4; ++n) {
        int idx = n * 256 + tid;
        int h = idx >> 6, r = idx & 63;
        size_t li = ((size_t)(bb * H_ + h)) * S_ + sbase + r;
        lp[idx] = ed[li] / lsum[li];
    }
    __syncthreads();

    f32x4 acc[2][4];
    #pragma unroll
    for (int i = 0; i < 2; ++i)
        #pragma unroll
        for (int j = 0; j < 4; ++j) acc[i][j] = (f32x4){0.f,0.f,0.f,0.f};

    for (int k0 = 0; k0 < E_; k0 += BK) {
        const int h = k0 >> 6;
        stage64<BN>(Wo + (size_t)bn * E_ + k0, lB, E_, wave, lane);   // DMA first
        // A: explicit scaled staging, same LDS layout (chunk q at offset q*16B)
        #pragma unroll
        for (int n = 0; n < 2; ++n) {
            int q = n * 256 + tid;
            int r = q >> 3, slot = q & 7;
            int c = slot ^ ((r >> 1) & 7);
            float p = lp[h * 64 + r];
            int4 pk = *(const int4*)(V + (size_t)(bm + r) * E_ + k0 + c * 8);
            u16* u = (u16*)&pk;
            #pragma unroll
            for (int jq = 0; jq < 8; ++jq) u[jq] = f2b(b2f(u[jq]) * p);
            *(int4*)(lA + (size_t)q * 8) = pk;
        }
        __syncthreads();
        #pragma unroll
        for (int s = 0; s < 2; ++s) {
            short8 af[2], bf[4];
            #pragma unroll
            for (int i = 0; i < 2; ++i) {
                int R = wm + i * 16 + l16;
                int sc = s * 4 + quad;
                af[i] = *(const short8*)&lA[R * 64 + ((sc ^ ((R >> 1) & 7)) * 8)];
            }
            #pragma unroll
            for (int j = 0; j < 4; ++j) {
                int R = wn + j * 16 + l16;
                int sc = s * 4 + quad;
                bf[j] = *(const short8*)&lB[R * 64 + ((sc ^ ((R >> 1) & 7)) * 8)];
            }
            #pragma unroll
            for (int i = 0; i < 2; ++i)
                #pragma unroll
                for (int j = 0; j < 4; ++j)
                    acc[i][j] = __builtin_amdgcn_mfma_f32_16x16x32_bf16(af[i], bf[j], acc[i][j], 0, 0, 0);
        }
        __syncthreads();
    }

    #pragma unroll
    for (int i = 0; i < 2; ++i)
        #pragma unroll
        for (int j = 0; j < 4; ++j) {
            int row0 = bm + wm + i * 16 + quad * 4;
            int col  = bn + wn + j * 16 + l16;
            #pragma unroll
            for (int r = 0; r < 4; ++r) {
                size_t idx = (size_t)(row0 + r) * E_ + col;
                Out[idx] = acc[i][j][r] + b2f(V[idx]);
            }
        }
}

// ---------------- attention l-rowsums: tiled exp(QK^T/32) pass ----------------
// Block = one 128x128 causal score tile (ii,jj) of one bh; 4352 blocks = 17/CU.
// K-tile (128x64) staged in LDS as TWO stacked 128x32 planes (f = k-half)
// with the 4-slot XOR swizzle -> 2-way-max bank conflicts.
// Each wave: 2 m-tiles x 8 n-tiles x K=64 -> 32 MFMAs, then exp + rowsum
// (mask + diag extraction on ii==jj blocks), one fp32 atomicAdd per row.
__global__ __launch_bounds__(256, 4)
void attn_tiles_kernel(const u16* __restrict__ Q, const u16* __restrict__ Kp,
                       float* __restrict__ lsum, float* __restrict__ ed)
{
    __shared__ u16 lK[128 * 64];             // 16 KB
    const int tau = blockIdx.x;              // 0..135 triangular tile index
    const int bh  = blockIdx.y;
    const int b = bh >> 4, h = bh & 15;
    int ii = 0;
    while ((ii + 1) * (ii + 2) / 2 <= tau) ++ii;
    const int jj = tau - ii * (ii + 1) / 2;
    const bool diag = (ii == jj);
    const int wave = threadIdx.x >> 6, lane = threadIdx.x & 63;
    const int quad = lane >> 4, l16 = lane & 15;
    const float CE = 0.04508422002778f;      // log2(e)/32

    // stage K rows jj*128..+127, cols h*64..+63 (1024 chunks, 4 rounds)
    const u16* kg = Kp + ((size_t)(b * S_) + jj * 128) * E_ + h * D_;
    #pragma unroll
    for (int m4 = 0; m4 < 4; ++m4) {
        int q = m4 * 256 + wave * 64 + lane;
        int slot = q & 3, hr = q >> 2;
        int f = hr >> 7, r = hr & 127;
        int c = f * 4 + (slot ^ ((r >> 1) & 3));
        const u16* g = kg + (size_t)r * E_ + c * 8;
        u16* l = lK + (size_t)(m4 * 256 + wave * 64) * 8;   // wave-uniform base
        __builtin_amdgcn_global_load_lds(
            (const __attribute__((address_space(1))) unsigned int*)g,
            (__attribute__((address_space(3))) unsigned int*)l, 16, 0, 0);
    }

    // Q A-frags direct from global: rows ii*128 + wave*32 + m*16 + l16
    short8 aq[2][2];
    #pragma unroll
    for (int m = 0; m < 2; ++m) {
        const u16* qp = Q + ((size_t)(b * S_) + ii * 128 + wave * 32 + m * 16 + l16) * E_
                        + h * D_ + quad * 8;
        aq[m][0] = *(const short8*)qp;
        aq[m][1] = *(const short8*)(qp + 32);
    }
    __syncthreads();

    f32x4 acc[2][8];
    #pragma unroll
    for (int m = 0; m < 2; ++m)
        #pragma unroll
        for (int n = 0; n < 8; ++n) acc[m][n] = (f32x4){0.f,0.f,0.f,0.f};

    #pragma unroll
    for (int nt = 0; nt < 8; ++nt) {
        int R = nt * 16 + l16;
        int sw = (R >> 1) & 3;
        short8 bk0 = *(const short8*)&lK[((0 * 128 + R) * 4 + (quad ^ sw)) * 8];
        short8 bk1 = *(const short8*)&lK[((1 * 128 + R) * 4 + (quad ^ sw)) * 8];
        #pragma unroll
        for (int m = 0; m < 2; ++m) {
            acc[m][nt] = __builtin_amdgcn_mfma_f32_16x16x32_bf16(aq[m][0], bk0, acc[m][nt], 0, 0, 0);
            acc[m][nt] = __builtin_amdgcn_mfma_f32_16x16x32_bf16(aq[m][1], bk1, acc[m][nt], 0, 0, 0);
        }
    }

    // exp, (mask/diag on diagonal blocks), rowsum
    float rs[2][4];
    #pragma unroll
    for (int m = 0; m < 2; ++m)
        #pragma unroll
        for (int r = 0; r < 4; ++r) rs[m][r] = 0.f;

    #pragma unroll
    for (int m = 0; m < 2; ++m)
        #pragma unroll
        for (int nt = 0; nt < 8; ++nt)
            #pragma unroll
            for (int r = 0; r < 4; ++r) {
                float e = ex2(acc[m][nt][r] * CE);
                if (diag) {
                    int srow = wave * 32 + m * 16 + quad * 4 + r;   // within tile
                    int tcol = nt * 16 + l16;
                    if (tcol > srow) e = 0.f;
                    if (tcol == srow)
                        ed[(size_t)bh * S_ + ii * 128 + srow] = e;
                }
                rs[m][r] += e;
            }

    #pragma unroll
    for (int m = 0; m < 2; ++m)
        #pragma unroll
        for (int r = 0; r < 4; ++r) {
            float v = rs[m][r];
            v += __shfl_xor(v, 1); v += __shfl_xor(v, 2);
            v += __shfl_xor(v, 4); v += __shfl_xor(v, 8);
            if (l16 == 0) {
                int srow = ii * 128 + wave * 32 + m * 16 + quad * 4 + r;
                atomicAdd(&lsum[(size_t)bh * S_ + srow], v);
            }
        }
}

extern "C" void kernel_launch(void* const* d_in, const int* in_sizes, int n_in,
                              void* d_out, int out_size, void* d_ws, size_t ws_size,
                              hipStream_t stream)
{
    const float* X  = (const float*)d_in[0];
    const float* Wq = (const float*)d_in[1];
    const float* Wk = (const float*)d_in[2];
    const float* Wv = (const float*)d_in[3];
    const float* Wo = (const float*)d_in[4];
    float* Out = (float*)d_out;

    u16* Xb  = (u16*)d_ws;
    u16* Wqb = Xb  + (size_t)M_ * E_;
    u16* Wkb = Wqb + (size_t)E_ * E_;
    u16* Wvb = Wkb + (size_t)E_ * E_;
    u16* Wob = Wvb + (size_t)E_ * E_;
    u16* Q   = Wob + (size_t)E_ * E_;
    u16* K   = Q   + (size_t)M_ * E_;
    u16* V   = K   + (size_t)M_ * E_;
    float* lsum = (float*)(V + (size_t)M_ * E_);     // [32][2048] fp32
    float* ed   = lsum + (size_t)B_ * H_ * S_;       // [32][2048] fp32

    cvt_kernel<<<dim3(8192 + 64), dim3(256), 0, stream>>>(X, Wq, Wk, Wv, Wo,
                                                          Xb, Wqb, Wkb, Wvb, Wob, lsum);
    qkv_kernel<<<dim3(M_/128, E_/BN, 3), dim3(256), 0, stream>>>(Xb, Wqb, Wkb, Wvb, Q, K, V);
    attn_tiles_kernel<<<dim3(136, B_*H_), dim3(256), 0, stream>>>(Q, K, lsum, ed);
    out_kernel<<<dim3(M_/64, E_/BN), dim3(256), 0, stream>>>(V, Wob, lsum, ed, Out);
}